// Round 12
// baseline (122.760 us; speedup 1.0000x reference)
//
#include <hip/hip_runtime.h>
#include <cmath>
#include <cstdint>

typedef __attribute__((ext_vector_type(8))) __bf16 bf16x8;
typedef __attribute__((ext_vector_type(16))) float f32x16;
typedef unsigned int u32;
typedef unsigned short u16;

constexpr int Bn = 4, Sn = 4096, Dn = 128;
constexpr int OSTR = 132;  // legacy path Oc row stride
constexpr float SCL2E = 0.08838834764831845f * 1.4426950408889634f;  // 1/sqrt(128)*log2(e)

#if __has_builtin(__builtin_amdgcn_exp2f)
#define EXP2F(x) __builtin_amdgcn_exp2f(x)
#else
#define EXP2F(x) exp2f(x)
#endif

__device__ __forceinline__ u32 pk2(float a, float b) {
  u32 r;
  asm("v_cvt_pk_bf16_f32 %0, %1, %2" : "=v"(r) : "v"(a), "v"(b));
  return r;
}

__device__ __forceinline__ void pl32swap(u32& a, u32& b) {
  asm("v_permlane32_swap_b32 %0, %1" : "+v"(a), "+v"(b));
}

// async 16B global -> LDS (linear dest = wave-uniform base + lane*16)
__device__ __forceinline__ void gload_lds16(const void* g, void* l) {
  __builtin_amdgcn_global_load_lds(
      (const __attribute__((address_space(1))) u32*)g,
      (__attribute__((address_space(3))) u32*)l, 16, 0, 0);
}

// ---- pre-pass: K,V -> bf16 in 32x32x16-MFMA fragment order, per (b,kt) 64-key tile ----
// Kf granule gk = (kc*4 + tile*2 + h)*32 + c  holds K[kt*64+tile*32+c][kc*16+h*8+j]
// Vf granule gv = (kc2*8 + nt*2 + h)*32 + c   holds V[kt*64+kc2*16+h*8+j][nt*32+c]
__launch_bounds__(256)
__global__ void prep_kv(const float* __restrict__ Kg, const float* __restrict__ Vg,
                        u16* __restrict__ Kf, u16* __restrict__ Vf) {
  __shared__ float Tl[64 * 132];
  const int kt = blockIdx.x, kind = blockIdx.y, b = blockIdx.z;
  const int tid = threadIdx.x;
  const size_t tileBase = ((size_t)b * 64 + kt) * 1024;  // granules (8 elems each)
  const float* src = (kind == 0 ? Kg : Vg) + ((size_t)b * Sn + kt * 64) * Dn;

  #pragma unroll
  for (int r = 0; r < 8; ++r) {
    const int idx = tid + r * 256;  // 2048 float4
    const int row = idx >> 5, col = (idx & 31) * 4;
    float4 v = *(const float4*)(src + (size_t)row * Dn + col);
    *(float4*)(Tl + row * 132 + col) = v;
  }
  __syncthreads();
  if (kind == 0) {
    #pragma unroll
    for (int r = 0; r < 4; ++r) {
      const int g = tid + r * 256;
      const int c = g & 31, h = (g >> 5) & 1, tile = (g >> 6) & 1, kc = g >> 7;
      const float* s = Tl + (tile * 32 + c) * 132 + kc * 16 + h * 8;
      float4 f0 = *(const float4*)(s);
      float4 f1 = *(const float4*)(s + 4);
      uint4 o;
      o.x = pk2(f0.x, f0.y); o.y = pk2(f0.z, f0.w);
      o.z = pk2(f1.x, f1.y); o.w = pk2(f1.z, f1.w);
      *(uint4*)(Kf + (tileBase + g) * 8) = o;
    }
  } else {
    #pragma unroll
    for (int r = 0; r < 4; ++r) {
      const int g = tid + r * 256;
      const int c = g & 31, h = (g >> 5) & 1, nt = (g >> 6) & 3, kc2 = g >> 8;
      const int key0 = kc2 * 16 + h * 8, dcol = nt * 32 + c;
      float x[8];
      #pragma unroll
      for (int j = 0; j < 8; ++j) x[j] = Tl[(key0 + j) * 132 + dcol];
      uint4 o;
      o.x = pk2(x[0], x[1]); o.y = pk2(x[2], x[3]);
      o.z = pk2(x[4], x[5]); o.w = pk2(x[6], x[7]);
      *(uint4*)(Vf + (tileBase + g) * 8) = o;
    }
  }
}

// ---- main: LDS-shared flash attention, SOFTWARE-PIPELINED (best verified: R7) ----
// Session record at this structure: R7 = 48.4us attn / 121.3us total, VGPR 116,
// no spill. R8 (merged QK||PV cluster), R10 (wave-phase stagger), R11 (pack-fused
// PV) all added live register state and regressed (spill or liveness stretch);
// R9's in-kernel split-K handoff broke correctness (cross-XCD coherence).
// This is the exact R7 body: region t overlaps QK(t+1) with SM(t)+PV(t):
//   region t: stage(t+2)->C | interleave{ QK(t+1) from B.K , SM(t) } | pack |
//             PV(t) from A.V | barrier | rotate(A,B,C)
// 3 LDS buffers (96KB, 1 block/CU, 8 waves); ping-pong S-accums; setprio on MFMA.
__launch_bounds__(512)
__global__ void attn_tile(const float* __restrict__ qg, const u16* __restrict__ Kf,
                          const u16* __restrict__ Vf, float* __restrict__ Of,
                          float* __restrict__ lw) {
  __shared__ __align__(16) u16 kv[3][16384];  // [buf][K 8192 u16 | V 8192 u16]

  const int tid = threadIdx.x;
  const int w = tid >> 6, lane = tid & 63;
  const int c = lane & 31, h = lane >> 5;
  // blockIdx.x = qg*16 + (b*4+ks): blocks sharing a (b,ks) K/V range share an XCD L2
  const int bks = blockIdx.x & 15, qg2 = blockIdx.x >> 4;
  const int b = bks >> 2, ks = bks & 3;
  const int q0 = qg2 * 256 + w * 32;

  const u16* Kb = Kf + ((size_t)b * 64 + ks * 16) * 8192;
  const u16* Vb = Vf + ((size_t)b * 64 + ks * 16) * 8192;

  // Q B-frags (scaled, packed) once per wave
  bf16x8 qf[8];
  {
    const float* Qr = qg + ((size_t)b * Sn + q0 + c) * Dn;
    #pragma unroll
    for (int kc = 0; kc < 8; ++kc) {
      float4 f0 = *(const float4*)(Qr + kc * 16 + h * 8);
      float4 f1 = *(const float4*)(Qr + kc * 16 + h * 8 + 4);
      uint4 t;
      t.x = pk2(f0.x * SCL2E, f0.y * SCL2E);
      t.y = pk2(f0.z * SCL2E, f0.w * SCL2E);
      t.z = pk2(f1.x * SCL2E, f1.y * SCL2E);
      t.w = pk2(f1.z * SCL2E, f1.w * SCL2E);
      qf[kc] = __builtin_bit_cast(bf16x8, t);
    }
  }

  f32x16 accO[4];
  #pragma unroll
  for (int nt = 0; nt < 4; ++nt)
    #pragma unroll
    for (int r = 0; r < 16; ++r) accO[nt][r] = 0.f;
  float l_i = 0.f;

  u16 *A = &kv[0][0], *B = &kv[1][0], *C = &kv[2][0];

#define STAGE(dst, t_) do {                                                    \
    const u16* kt_ = Kb + (size_t)(t_) * 8192;                                 \
    const u16* vt_ = Vb + (size_t)(t_) * 8192;                                 \
    gload_lds16(kt_ + tid * 8, (dst) + tid * 8);                               \
    gload_lds16(kt_ + 4096 + tid * 8, (dst) + 4096 + tid * 8);                 \
    gload_lds16(vt_ + tid * 8, (dst) + 8192 + tid * 8);                        \
    gload_lds16(vt_ + 4096 + tid * 8, (dst) + 12288 + tid * 8);                \
  } while (0)

  STAGE(A, 0);
  STAGE(B, 1);
  __syncthreads();  // full drain: tiles 0 and 1 resident

  f32x16 sA0, sA1, sB0, sB1;
  // prologue QK(0) from A.K
  {
    #pragma unroll
    for (int r = 0; r < 16; ++r) { sA0[r] = 0.f; sA1[r] = 0.f; }
    __builtin_amdgcn_s_setprio(1);
    #pragma unroll
    for (int kc = 0; kc < 8; ++kc) {
      uint4 a0 = *(const uint4*)(A + (size_t)((kc * 4 + 0 + h) * 32 + c) * 8);
      uint4 a1 = *(const uint4*)(A + (size_t)((kc * 4 + 2 + h) * 32 + c) * 8);
      sA0 = __builtin_amdgcn_mfma_f32_32x32x16_bf16(__builtin_bit_cast(bf16x8, a0), qf[kc], sA0, 0, 0, 0);
      sA1 = __builtin_amdgcn_mfma_f32_32x32x16_bf16(__builtin_bit_cast(bf16x8, a1), qf[kc], sA1, 0, 0, 0);
    }
    __builtin_amdgcn_s_setprio(0);
  }

// region t: stage(t+2)->C; QK(t+1) from B interleaved with SM(t) on cur;
// pack; PV(t) from A.V; barrier; rotate buffers.
#define REGION(t_, cur0, cur1, nx0, nx1) do {                                  \
    if ((t_) + 2 < 16) STAGE(C, (t_) + 2);                                     \
    float rs0 = 0.f, rs1 = 0.f;                                                \
    if ((t_) + 1 < 16) {                                                       \
      _Pragma("unroll")                                                        \
      for (int r = 0; r < 16; ++r) { (nx0)[r] = 0.f; (nx1)[r] = 0.f; }         \
      _Pragma("unroll")                                                        \
      for (int kc = 0; kc < 8; ++kc) {                                         \
        uint4 a0 = *(const uint4*)(B + (size_t)((kc * 4 + 0 + h) * 32 + c) * 8); \
        uint4 a1 = *(const uint4*)(B + (size_t)((kc * 4 + 2 + h) * 32 + c) * 8); \
        (nx0) = __builtin_amdgcn_mfma_f32_32x32x16_bf16(__builtin_bit_cast(bf16x8, a0), qf[kc], (nx0), 0, 0, 0); \
        (nx1) = __builtin_amdgcn_mfma_f32_32x32x16_bf16(__builtin_bit_cast(bf16x8, a1), qf[kc], (nx1), 0, 0, 0); \
        float e0 = EXP2F((cur0)[2 * kc]);     rs0 += e0; (cur0)[2 * kc] = e0;     \
        float e1 = EXP2F((cur0)[2 * kc + 1]); rs0 += e1; (cur0)[2 * kc + 1] = e1; \
        float e2 = EXP2F((cur1)[2 * kc]);     rs1 += e2; (cur1)[2 * kc] = e2;     \
        float e3 = EXP2F((cur1)[2 * kc + 1]); rs1 += e3; (cur1)[2 * kc + 1] = e3; \
      }                                                                        \
    } else {                                                                   \
      _Pragma("unroll")                                                        \
      for (int r = 0; r < 16; ++r) {                                           \
        float e0 = EXP2F((cur0)[r]); rs0 += e0; (cur0)[r] = e0;                \
        float e1 = EXP2F((cur1)[r]); rs1 += e1; (cur1)[r] = e1;                \
      }                                                                        \
    }                                                                          \
    l_i += rs0 + rs1;                                                          \
    u32 p0_[8], p1_[8];                                                        \
    _Pragma("unroll")                                                          \
    for (int i_ = 0; i_ < 8; ++i_) {                                           \
      p0_[i_] = pk2((cur0)[2 * i_], (cur0)[2 * i_ + 1]);                       \
      p1_[i_] = pk2((cur1)[2 * i_], (cur1)[2 * i_ + 1]);                       \
    }                                                                          \
    __builtin_amdgcn_s_setprio(1);                                             \
    _Pragma("unroll")                                                          \
    for (int kc2 = 0; kc2 < 4; ++kc2) {                                        \
      const int bb = (kc2 & 1) * 4;                                            \
      u32 x0 = (kc2 < 2) ? p0_[bb] : p1_[bb];                                  \
      u32 x1 = (kc2 < 2) ? p0_[bb + 1] : p1_[bb + 1];                          \
      u32 x2 = (kc2 < 2) ? p0_[bb + 2] : p1_[bb + 2];                          \
      u32 x3 = (kc2 < 2) ? p0_[bb + 3] : p1_[bb + 3];                          \
      pl32swap(x0, x2);                                                        \
      pl32swap(x1, x3);                                                        \
      uint4 afi; afi.x = x0; afi.y = x1; afi.z = x2; afi.w = x3;               \
      bf16x8 af = __builtin_bit_cast(bf16x8, afi);                             \
      _Pragma("unroll")                                                        \
      for (int nt = 0; nt < 4; ++nt) {                                         \
        uint4 av = *(const uint4*)(A + 8192 + (size_t)((kc2 * 8 + nt * 2 + h) * 32 + c) * 8); \
        accO[nt] = __builtin_amdgcn_mfma_f32_32x32x16_bf16(__builtin_bit_cast(bf16x8, av), af, accO[nt], 0, 0, 0); \
      }                                                                        \
    }                                                                          \
    __builtin_amdgcn_s_setprio(0);                                             \
    __syncthreads();                                                           \
    { u16* tmp_ = A; A = B; B = C; C = tmp_; }                                 \
  } while (0)

  #pragma unroll 1
  for (int i = 0; i < 8; ++i) {
    REGION(2 * i, sA0, sA1, sB0, sB1);
    REGION(2 * i + 1, sB0, sB1, sA0, sA1);
  }
#undef REGION
#undef STAGE

  // ---- partial l and unnormalized partial O -> workspace ----
  // accO[nt] reg r: O row q = q0+c, d = nt*32 + (r&3) + 8*(r>>2) + 4*h
  l_i += __shfl_xor(l_i, 32);
  const size_t rowbase = (size_t)ks * 16384 + (size_t)b * 4096 + q0;
  if (h == 0) lw[rowbase + c] = l_i;
  float* op = Of + (rowbase + c) * 128;
  #pragma unroll
  for (int nt = 0; nt < 4; ++nt)
    #pragma unroll
    for (int rq = 0; rq < 4; ++rq) {
      float4 wv = {accO[nt][4 * rq + 0], accO[nt][4 * rq + 1],
                   accO[nt][4 * rq + 2], accO[nt][4 * rq + 3]};
      *(float4*)(op + nt * 32 + rq * 8 + 4 * h) = wv;
    }
}

// ---- combine: out[row][d] = sum_ks Of / sum_ks l (kernel boundary = coherence) ----
__launch_bounds__(256)
__global__ void combine(const float* __restrict__ Of, const float* __restrict__ lw,
                        float* __restrict__ Og) {
  const int gid = blockIdx.x * 256 + threadIdx.x;  // 262144 threads
  const int row = gid >> 4;
  const int d0 = (gid & 15) * 8;
  float ls = 0.f;
  #pragma unroll
  for (int k2 = 0; k2 < 4; ++k2) ls += lw[(size_t)k2 * 16384 + row];
  const float inv = 1.f / ls;
  float a[8] = {0.f, 0.f, 0.f, 0.f, 0.f, 0.f, 0.f, 0.f};
  #pragma unroll
  for (int k2 = 0; k2 < 4; ++k2) {
    const float* p = Of + ((size_t)k2 * 16384 + row) * 128 + d0;
    float4 v0 = *(const float4*)(p);
    float4 v1 = *(const float4*)(p + 4);
    a[0] += v0.x; a[1] += v0.y; a[2] += v0.z; a[3] += v0.w;
    a[4] += v1.x; a[5] += v1.y; a[6] += v1.z; a[7] += v1.w;
  }
  float* op = Og + (size_t)row * 128 + d0;
  float4 o0 = {a[0] * inv, a[1] * inv, a[2] * inv, a[3] * inv};
  float4 o1 = {a[4] * inv, a[5] * inv, a[6] * inv, a[7] * inv};
  *(float4*)(op) = o0;
  *(float4*)(op + 4) = o1;
}

// ---- legacy R5 kernel (fallback if workspace too small for partials) ----
__launch_bounds__(256, 2)
__global__ void attn_legacy(const float* __restrict__ qg, const u16* __restrict__ Kf,
                            const u16* __restrict__ Vf, float* __restrict__ Og) {
  __shared__ __align__(16) unsigned char lds[68608];
  float* Oc = (float*)lds;
  float* ml = (float*)(lds + 67584);

  const int tid = threadIdx.x;
  const int kp = tid >> 6, lane = tid & 63;
  const int c = lane & 31, h = lane >> 5;
  const int b = blockIdx.x & 3;
  const int q0 = (blockIdx.x >> 2) * 32;

  const u16* Kb = Kf + ((size_t)b * 64) * 1024 * 8;
  const u16* Vb = Vf + ((size_t)b * 64) * 1024 * 8;

  bf16x8 qf[8];
  {
    const float* Qr = qg + ((size_t)b * Sn + q0 + c) * Dn;
    #pragma unroll
    for (int kc = 0; kc < 8; ++kc) {
      float4 f0 = *(const float4*)(Qr + kc * 16 + h * 8);
      float4 f1 = *(const float4*)(Qr + kc * 16 + h * 8 + 4);
      uint4 t;
      t.x = pk2(f0.x * SCL2E, f0.y * SCL2E);
      t.y = pk2(f0.z * SCL2E, f0.w * SCL2E);
      t.z = pk2(f1.x * SCL2E, f1.y * SCL2E);
      t.w = pk2(f1.z * SCL2E, f1.w * SCL2E);
      qf[kc] = __builtin_bit_cast(bf16x8, t);
    }
  }

  f32x16 accO[4];
  #pragma unroll
  for (int nt = 0; nt < 4; ++nt)
    #pragma unroll
    for (int r = 0; r < 16; ++r) accO[nt][r] = 0.f;
  float l_i = 0.f;

  #pragma unroll 1
  for (int t8 = 0; t8 < 16; ++t8) {
    const int kt = kp * 16 + t8;
    const u16* Kt = Kb + (size_t)kt * 8192;
    const u16* Vt = Vb + (size_t)kt * 8192;

    uint4 ka[8], kb[8];
    #pragma unroll
    for (int kc = 0; kc < 4; ++kc) {
      ka[2 * kc + 0] = *(const uint4*)(Kt + (size_t)((kc * 4 + 0 + h) * 32 + c) * 8);
      ka[2 * kc + 1] = *(const uint4*)(Kt + (size_t)((kc * 4 + 2 + h) * 32 + c) * 8);
    }
    #pragma unroll
    for (int kc = 4; kc < 8; ++kc) {
      kb[2 * (kc - 4) + 0] = *(const uint4*)(Kt + (size_t)((kc * 4 + 0 + h) * 32 + c) * 8);
      kb[2 * (kc - 4) + 1] = *(const uint4*)(Kt + (size_t)((kc * 4 + 2 + h) * 32 + c) * 8);
    }

    f32x16 sa0, sa1;
    #pragma unroll
    for (int r = 0; r < 16; ++r) { sa0[r] = 0.f; sa1[r] = 0.f; }
    #pragma unroll
    for (int kc = 0; kc < 4; ++kc) {
      sa0 = __builtin_amdgcn_mfma_f32_32x32x16_bf16(__builtin_bit_cast(bf16x8, ka[2 * kc + 0]), qf[kc], sa0, 0, 0, 0);
      sa1 = __builtin_amdgcn_mfma_f32_32x32x16_bf16(__builtin_bit_cast(bf16x8, ka[2 * kc + 1]), qf[kc], sa1, 0, 0, 0);
    }
    uint4 va[8];
    #pragma unroll
    for (int kc2 = 0; kc2 < 2; ++kc2)
      #pragma unroll
      for (int nt = 0; nt < 4; ++nt)
        va[kc2 * 4 + nt] = *(const uint4*)(Vt + (size_t)((kc2 * 8 + nt * 2 + h) * 32 + c) * 8);
    #pragma unroll
    for (int kc = 4; kc < 8; ++kc) {
      sa0 = __builtin_amdgcn_mfma_f32_32x32x16_bf16(__builtin_bit_cast(bf16x8, kb[2 * (kc - 4) + 0]), qf[kc], sa0, 0, 0, 0);
      sa1 = __builtin_amdgcn_mfma_f32_32x32x16_bf16(__builtin_bit_cast(bf16x8, kb[2 * (kc - 4) + 1]), qf[kc], sa1, 0, 0, 0);
    }
    uint4 vb[8];
    #pragma unroll
    for (int kc2 = 2; kc2 < 4; ++kc2)
      #pragma unroll
      for (int nt = 0; nt < 4; ++nt)
        vb[(kc2 - 2) * 4 + nt] = *(const uint4*)(Vt + (size_t)((kc2 * 8 + nt * 2 + h) * 32 + c) * 8);

    float rs0 = 0.f, rs1 = 0.f;
    #pragma unroll
    for (int r = 0; r < 16; ++r) { sa0[r] = exp2f(sa0[r]); rs0 += sa0[r]; }
    #pragma unroll
    for (int r = 0; r < 16; ++r) { sa1[r] = exp2f(sa1[r]); rs1 += sa1[r]; }
    l_i += rs0 + rs1;

    u32 pk2v[2][8];
    #pragma unroll
    for (int i = 0; i < 8; ++i) {
      pk2v[0][i] = pk2(sa0[2 * i], sa0[2 * i + 1]);
      pk2v[1][i] = pk2(sa1[2 * i], sa1[2 * i + 1]);
    }

    #pragma unroll
    for (int kc2 = 0; kc2 < 4; ++kc2) {
      const int t = kc2 >> 1;
      const int bb = (kc2 & 1) * 4;
      u32 x0 = pk2v[t][bb], x1 = pk2v[t][bb + 1], x2 = pk2v[t][bb + 2], x3 = pk2v[t][bb + 3];
      pl32swap(x0, x2);
      pl32swap(x1, x3);
      uint4 afi; afi.x = x0; afi.y = x1; afi.z = x2; afi.w = x3;
      bf16x8 af = __builtin_bit_cast(bf16x8, afi);
      const uint4* vsrc = (kc2 < 2) ? &va[kc2 * 4] : &vb[(kc2 - 2) * 4];
      #pragma unroll
      for (int nt = 0; nt < 4; ++nt) {
        accO[nt] = __builtin_amdgcn_mfma_f32_32x32x16_bf16(__builtin_bit_cast(bf16x8, vsrc[nt]), af, accO[nt], 0, 0, 0);
      }
    }
  }

  l_i += __shfl_xor(l_i, 32);
  __syncthreads();
  {
    float* od = Oc + (size_t)(kp * 32) * OSTR;
    #pragma unroll
    for (int nt = 0; nt < 4; ++nt)
      #pragma unroll
      for (int r = 0; r < 16; ++r) {
        const int dr = (r & 3) + 8 * (r >> 2) + 4 * h;
        od[c * OSTR + nt * 32 + dr] = accO[nt][r];
      }
    if (h == 0) ml[kp * 32 + c] = l_i;
  }
  __syncthreads();
  {
    const int row = tid >> 3;
    const int d0 = (tid & 7) * 16;
    float lsum = 0.f;
    #pragma unroll
    for (int k2 = 0; k2 < 4; ++k2) lsum += ml[k2 * 32 + row];
    const float inv = 1.f / lsum;
    float4 acc[4];
    #pragma unroll
    for (int j = 0; j < 4; ++j) acc[j] = float4{0.f, 0.f, 0.f, 0.f};
    #pragma unroll
    for (int k2 = 0; k2 < 4; ++k2) {
      const float* oc = Oc + (size_t)(k2 * 32 + row) * OSTR + d0;
      #pragma unroll
      for (int j = 0; j < 4; ++j) {
        float4 vv = *(const float4*)(oc + 4 * j);
        acc[j].x += vv.x; acc[j].y += vv.y;
        acc[j].z += vv.z; acc[j].w += vv.w;
      }
    }
    float* op = Og + ((size_t)b * Sn + q0 + row) * Dn + d0;
    #pragma unroll
    for (int j = 0; j < 4; ++j) {
      float4 o = {acc[j].x * inv, acc[j].y * inv, acc[j].z * inv, acc[j].w * inv};
      *(float4*)(op + 4 * j) = o;
    }
  }
}

extern "C" void kernel_launch(void* const* d_in, const int* in_sizes, int n_in,
                              void* d_out, int out_size, void* d_ws, size_t ws_size,
                              hipStream_t stream) {
  const float* q = (const float*)d_in[0];
  const float* k = (const float*)d_in[1];
  const float* v = (const float*)d_in[2];
  float* out = (float*)d_out;
  const size_t N = (size_t)Bn * Sn * Dn;  // 2,097,152 elems
  u16* Kf = (u16*)d_ws;                   // 4 MB
  u16* Vf = Kf + N;                       // 4 MB
  float* Of = (float*)(Vf + N);           // 32 MB: [4 ks][16384 rows][128 d]
  float* lwp = Of + 4 * N;                // 256 KB: [4 ks][16384 rows]
  const size_t need = 4 * N + 16 * N + 16 * (size_t)Bn * Sn;

  prep_kv<<<dim3(Sn / 64, 2, Bn), dim3(256), 0, stream>>>(k, v, Kf, Vf);
  if (ws_size >= need) {
    attn_tile<<<dim3(256), dim3(512), 0, stream>>>(q, Kf, Vf, Of, lwp);
    combine<<<dim3(1024), dim3(256), 0, stream>>>(Of, lwp, out);
  } else {
    attn_legacy<<<dim3((Sn / 32) * Bn), dim3(256), 0, stream>>>(q, Kf, Vf, out);
  }
}

// Round 13
// 118.844 us; speedup vs baseline: 1.0329x; 1.0329x over previous
//
#include <hip/hip_runtime.h>
#include <cmath>
#include <cstdint>

typedef __attribute__((ext_vector_type(8))) __bf16 bf16x8;
typedef __attribute__((ext_vector_type(16))) float f32x16;
typedef unsigned int u32;
typedef unsigned short u16;

constexpr int Bn = 4, Sn = 4096, Dn = 128;
constexpr int OSTR = 132;  // legacy path Oc row stride
constexpr float SCL2E = 0.08838834764831845f * 1.4426950408889634f;  // 1/sqrt(128)*log2(e)

#if __has_builtin(__builtin_amdgcn_exp2f)
#define EXP2F(x) __builtin_amdgcn_exp2f(x)
#else
#define EXP2F(x) exp2f(x)
#endif

__device__ __forceinline__ u32 pk2(float a, float b) {
  u32 r;
  asm("v_cvt_pk_bf16_f32 %0, %1, %2" : "=v"(r) : "v"(a), "v"(b));
  return r;
}

// unpack bf16 pair (lo16 = first, hi16 = second) back to f32
__device__ __forceinline__ float lo2f(u32 w) { return __builtin_bit_cast(float, w << 16); }
__device__ __forceinline__ float hi2f(u32 w) { return __builtin_bit_cast(float, w & 0xffff0000u); }

__device__ __forceinline__ void pl32swap(u32& a, u32& b) {
  asm("v_permlane32_swap_b32 %0, %1" : "+v"(a), "+v"(b));
}

// async 16B global -> LDS (linear dest = wave-uniform base + lane*16)
__device__ __forceinline__ void gload_lds16(const void* g, void* l) {
  __builtin_amdgcn_global_load_lds(
      (const __attribute__((address_space(1))) u32*)g,
      (__attribute__((address_space(3))) u32*)l, 16, 0, 0);
}

// ---- pre-pass: K,V -> bf16 in 32x32x16-MFMA fragment order, per (b,kt) 64-key tile ----
// Kf granule gk = (kc*4 + tile*2 + h)*32 + c  holds K[kt*64+tile*32+c][kc*16+h*8+j]
// Vf granule gv = (kc2*8 + nt*2 + h)*32 + c   holds V[kt*64+kc2*16+h*8+j][nt*32+c]
__launch_bounds__(256)
__global__ void prep_kv(const float* __restrict__ Kg, const float* __restrict__ Vg,
                        u16* __restrict__ Kf, u16* __restrict__ Vf) {
  __shared__ float Tl[64 * 132];
  const int kt = blockIdx.x, kind = blockIdx.y, b = blockIdx.z;
  const int tid = threadIdx.x;
  const size_t tileBase = ((size_t)b * 64 + kt) * 1024;  // granules (8 elems each)
  const float* src = (kind == 0 ? Kg : Vg) + ((size_t)b * Sn + kt * 64) * Dn;

  #pragma unroll
  for (int r = 0; r < 8; ++r) {
    const int idx = tid + r * 256;  // 2048 float4
    const int row = idx >> 5, col = (idx & 31) * 4;
    float4 v = *(const float4*)(src + (size_t)row * Dn + col);
    *(float4*)(Tl + row * 132 + col) = v;
  }
  __syncthreads();
  if (kind == 0) {
    #pragma unroll
    for (int r = 0; r < 4; ++r) {
      const int g = tid + r * 256;
      const int c = g & 31, h = (g >> 5) & 1, tile = (g >> 6) & 1, kc = g >> 7;
      const float* s = Tl + (tile * 32 + c) * 132 + kc * 16 + h * 8;
      float4 f0 = *(const float4*)(s);
      float4 f1 = *(const float4*)(s + 4);
      uint4 o;
      o.x = pk2(f0.x, f0.y); o.y = pk2(f0.z, f0.w);
      o.z = pk2(f1.x, f1.y); o.w = pk2(f1.z, f1.w);
      *(uint4*)(Kf + (tileBase + g) * 8) = o;
    }
  } else {
    #pragma unroll
    for (int r = 0; r < 4; ++r) {
      const int g = tid + r * 256;
      const int c = g & 31, h = (g >> 5) & 1, nt = (g >> 6) & 3, kc2 = g >> 8;
      const int key0 = kc2 * 16 + h * 8, dcol = nt * 32 + c;
      float x[8];
      #pragma unroll
      for (int j = 0; j < 8; ++j) x[j] = Tl[(key0 + j) * 132 + dcol];
      uint4 o;
      o.x = pk2(x[0], x[1]); o.y = pk2(x[2], x[3]);
      o.z = pk2(x[4], x[5]); o.w = pk2(x[6], x[7]);
      *(uint4*)(Vf + (tileBase + g) * 8) = o;
    }
  }
}

// ---- main: LDS-shared flash attention, SOFTWARE-PIPELINED (verified R7 body) ----
// Session record: R7/R12 = 48.4-49us attn, VGPR 116, no spill. R8/R10/R11 (more
// concurrent register state) and R9 (in-kernel cross-XCD combine) all regressed.
// Compute body byte-identical to R7. Only change vs R12: partial O stored as BF16
// (numerics: partial-storage error scales as |O_partial|*eps/l_total ~ 4e-5,
// far under the 3.07e-3 threshold) -> attn write 32->16MB, combine read 32->16MB.
//   region t: stage(t+2)->C | interleave{ QK(t+1) from B.K , SM(t) } | pack |
//             PV(t) from A.V | barrier | rotate(A,B,C)
__launch_bounds__(512)
__global__ void attn_tile(const float* __restrict__ qg, const u16* __restrict__ Kf,
                          const u16* __restrict__ Vf, u16* __restrict__ Of,
                          float* __restrict__ lw) {
  __shared__ __align__(16) u16 kv[3][16384];  // [buf][K 8192 u16 | V 8192 u16]

  const int tid = threadIdx.x;
  const int w = tid >> 6, lane = tid & 63;
  const int c = lane & 31, h = lane >> 5;
  // blockIdx.x = qg*16 + (b*4+ks): blocks sharing a (b,ks) K/V range share an XCD L2
  const int bks = blockIdx.x & 15, qg2 = blockIdx.x >> 4;
  const int b = bks >> 2, ks = bks & 3;
  const int q0 = qg2 * 256 + w * 32;

  const u16* Kb = Kf + ((size_t)b * 64 + ks * 16) * 8192;
  const u16* Vb = Vf + ((size_t)b * 64 + ks * 16) * 8192;

  // Q B-frags (scaled, packed) once per wave
  bf16x8 qf[8];
  {
    const float* Qr = qg + ((size_t)b * Sn + q0 + c) * Dn;
    #pragma unroll
    for (int kc = 0; kc < 8; ++kc) {
      float4 f0 = *(const float4*)(Qr + kc * 16 + h * 8);
      float4 f1 = *(const float4*)(Qr + kc * 16 + h * 8 + 4);
      uint4 t;
      t.x = pk2(f0.x * SCL2E, f0.y * SCL2E);
      t.y = pk2(f0.z * SCL2E, f0.w * SCL2E);
      t.z = pk2(f1.x * SCL2E, f1.y * SCL2E);
      t.w = pk2(f1.z * SCL2E, f1.w * SCL2E);
      qf[kc] = __builtin_bit_cast(bf16x8, t);
    }
  }

  f32x16 accO[4];
  #pragma unroll
  for (int nt = 0; nt < 4; ++nt)
    #pragma unroll
    for (int r = 0; r < 16; ++r) accO[nt][r] = 0.f;
  float l_i = 0.f;

  u16 *A = &kv[0][0], *B = &kv[1][0], *C = &kv[2][0];

#define STAGE(dst, t_) do {                                                    \
    const u16* kt_ = Kb + (size_t)(t_) * 8192;                                 \
    const u16* vt_ = Vb + (size_t)(t_) * 8192;                                 \
    gload_lds16(kt_ + tid * 8, (dst) + tid * 8);                               \
    gload_lds16(kt_ + 4096 + tid * 8, (dst) + 4096 + tid * 8);                 \
    gload_lds16(vt_ + tid * 8, (dst) + 8192 + tid * 8);                        \
    gload_lds16(vt_ + 4096 + tid * 8, (dst) + 12288 + tid * 8);                \
  } while (0)

  STAGE(A, 0);
  STAGE(B, 1);
  __syncthreads();  // full drain: tiles 0 and 1 resident

  f32x16 sA0, sA1, sB0, sB1;
  // prologue QK(0) from A.K
  {
    #pragma unroll
    for (int r = 0; r < 16; ++r) { sA0[r] = 0.f; sA1[r] = 0.f; }
    __builtin_amdgcn_s_setprio(1);
    #pragma unroll
    for (int kc = 0; kc < 8; ++kc) {
      uint4 a0 = *(const uint4*)(A + (size_t)((kc * 4 + 0 + h) * 32 + c) * 8);
      uint4 a1 = *(const uint4*)(A + (size_t)((kc * 4 + 2 + h) * 32 + c) * 8);
      sA0 = __builtin_amdgcn_mfma_f32_32x32x16_bf16(__builtin_bit_cast(bf16x8, a0), qf[kc], sA0, 0, 0, 0);
      sA1 = __builtin_amdgcn_mfma_f32_32x32x16_bf16(__builtin_bit_cast(bf16x8, a1), qf[kc], sA1, 0, 0, 0);
    }
    __builtin_amdgcn_s_setprio(0);
  }

// region t: stage(t+2)->C; QK(t+1) from B interleaved with SM(t) on cur;
// pack; PV(t) from A.V; barrier; rotate buffers.
#define REGION(t_, cur0, cur1, nx0, nx1) do {                                  \
    if ((t_) + 2 < 16) STAGE(C, (t_) + 2);                                     \
    float rs0 = 0.f, rs1 = 0.f;                                                \
    if ((t_) + 1 < 16) {                                                       \
      _Pragma("unroll")                                                        \
      for (int r = 0; r < 16; ++r) { (nx0)[r] = 0.f; (nx1)[r] = 0.f; }         \
      _Pragma("unroll")                                                        \
      for (int kc = 0; kc < 8; ++kc) {                                         \
        uint4 a0 = *(const uint4*)(B + (size_t)((kc * 4 + 0 + h) * 32 + c) * 8); \
        uint4 a1 = *(const uint4*)(B + (size_t)((kc * 4 + 2 + h) * 32 + c) * 8); \
        (nx0) = __builtin_amdgcn_mfma_f32_32x32x16_bf16(__builtin_bit_cast(bf16x8, a0), qf[kc], (nx0), 0, 0, 0); \
        (nx1) = __builtin_amdgcn_mfma_f32_32x32x16_bf16(__builtin_bit_cast(bf16x8, a1), qf[kc], (nx1), 0, 0, 0); \
        float e0 = EXP2F((cur0)[2 * kc]);     rs0 += e0; (cur0)[2 * kc] = e0;     \
        float e1 = EXP2F((cur0)[2 * kc + 1]); rs0 += e1; (cur0)[2 * kc + 1] = e1; \
        float e2 = EXP2F((cur1)[2 * kc]);     rs1 += e2; (cur1)[2 * kc] = e2;     \
        float e3 = EXP2F((cur1)[2 * kc + 1]); rs1 += e3; (cur1)[2 * kc + 1] = e3; \
      }                                                                        \
    } else {                                                                   \
      _Pragma("unroll")                                                        \
      for (int r = 0; r < 16; ++r) {                                           \
        float e0 = EXP2F((cur0)[r]); rs0 += e0; (cur0)[r] = e0;                \
        float e1 = EXP2F((cur1)[r]); rs1 += e1; (cur1)[r] = e1;                \
      }                                                                        \
    }                                                                          \
    l_i += rs0 + rs1;                                                          \
    u32 p0_[8], p1_[8];                                                        \
    _Pragma("unroll")                                                          \
    for (int i_ = 0; i_ < 8; ++i_) {                                           \
      p0_[i_] = pk2((cur0)[2 * i_], (cur0)[2 * i_ + 1]);                       \
      p1_[i_] = pk2((cur1)[2 * i_], (cur1)[2 * i_ + 1]);                       \
    }                                                                          \
    __builtin_amdgcn_s_setprio(1);                                             \
    _Pragma("unroll")                                                          \
    for (int kc2 = 0; kc2 < 4; ++kc2) {                                        \
      const int bb = (kc2 & 1) * 4;                                            \
      u32 x0 = (kc2 < 2) ? p0_[bb] : p1_[bb];                                  \
      u32 x1 = (kc2 < 2) ? p0_[bb + 1] : p1_[bb + 1];                          \
      u32 x2 = (kc2 < 2) ? p0_[bb + 2] : p1_[bb + 2];                          \
      u32 x3 = (kc2 < 2) ? p0_[bb + 3] : p1_[bb + 3];                          \
      pl32swap(x0, x2);                                                        \
      pl32swap(x1, x3);                                                        \
      uint4 afi; afi.x = x0; afi.y = x1; afi.z = x2; afi.w = x3;               \
      bf16x8 af = __builtin_bit_cast(bf16x8, afi);                             \
      _Pragma("unroll")                                                        \
      for (int nt = 0; nt < 4; ++nt) {                                         \
        uint4 av = *(const uint4*)(A + 8192 + (size_t)((kc2 * 8 + nt * 2 + h) * 32 + c) * 8); \
        accO[nt] = __builtin_amdgcn_mfma_f32_32x32x16_bf16(__builtin_bit_cast(bf16x8, av), af, accO[nt], 0, 0, 0); \
      }                                                                        \
    }                                                                          \
    __builtin_amdgcn_s_setprio(0);                                             \
    __syncthreads();                                                           \
    { u16* tmp_ = A; A = B; B = C; C = tmp_; }                                 \
  } while (0)

  #pragma unroll 1
  for (int i = 0; i < 8; ++i) {
    REGION(2 * i, sA0, sA1, sB0, sB1);
    REGION(2 * i + 1, sB0, sB1, sA0, sA1);
  }
#undef REGION
#undef STAGE

  // ---- partial l (f32) and unnormalized partial O (bf16-packed) -> workspace ----
  // accO[nt] reg r: O row q = q0+c, d = nt*32 + (r&3) + 8*(r>>2) + 4*h.
  // Four consecutive regs (4rq..4rq+3) = d offsets +0..+3 -> 2 pk2 words (8B store).
  l_i += __shfl_xor(l_i, 32);
  const size_t rowbase = (size_t)ks * 16384 + (size_t)b * 4096 + q0;
  if (h == 0) lw[rowbase + c] = l_i;
  u16* op = Of + (rowbase + c) * 128;
  #pragma unroll
  for (int nt = 0; nt < 4; ++nt)
    #pragma unroll
    for (int rq = 0; rq < 4; ++rq) {
      uint2 wv;
      wv.x = pk2(accO[nt][4 * rq + 0], accO[nt][4 * rq + 1]);
      wv.y = pk2(accO[nt][4 * rq + 2], accO[nt][4 * rq + 3]);
      *(uint2*)(op + nt * 32 + rq * 8 + 4 * h) = wv;
    }
}

// ---- combine: out[row][d] = sum_ks Of / sum_ks l (kernel boundary = coherence) ----
__launch_bounds__(256)
__global__ void combine(const u16* __restrict__ Of, const float* __restrict__ lw,
                        float* __restrict__ Og) {
  const int gid = blockIdx.x * 256 + threadIdx.x;  // 262144 threads
  const int row = gid >> 4;
  const int d0 = (gid & 15) * 8;
  float ls = 0.f;
  #pragma unroll
  for (int k2 = 0; k2 < 4; ++k2) ls += lw[(size_t)k2 * 16384 + row];
  const float inv = 1.f / ls;
  float a[8] = {0.f, 0.f, 0.f, 0.f, 0.f, 0.f, 0.f, 0.f};
  #pragma unroll
  for (int k2 = 0; k2 < 4; ++k2) {
    uint4 v = *(const uint4*)(Of + ((size_t)k2 * 16384 + row) * 128 + d0);
    a[0] += lo2f(v.x); a[1] += hi2f(v.x);
    a[2] += lo2f(v.y); a[3] += hi2f(v.y);
    a[4] += lo2f(v.z); a[5] += hi2f(v.z);
    a[6] += lo2f(v.w); a[7] += hi2f(v.w);
  }
  float* op = Og + (size_t)row * 128 + d0;
  float4 o0 = {a[0] * inv, a[1] * inv, a[2] * inv, a[3] * inv};
  float4 o1 = {a[4] * inv, a[5] * inv, a[6] * inv, a[7] * inv};
  *(float4*)(op) = o0;
  *(float4*)(op + 4) = o1;
}

// ---- legacy R5 kernel (fallback if workspace too small for partials) ----
__launch_bounds__(256, 2)
__global__ void attn_legacy(const float* __restrict__ qg, const u16* __restrict__ Kf,
                            const u16* __restrict__ Vf, float* __restrict__ Og) {
  __shared__ __align__(16) unsigned char lds[68608];
  float* Oc = (float*)lds;
  float* ml = (float*)(lds + 67584);

  const int tid = threadIdx.x;
  const int kp = tid >> 6, lane = tid & 63;
  const int c = lane & 31, h = lane >> 5;
  const int b = blockIdx.x & 3;
  const int q0 = (blockIdx.x >> 2) * 32;

  const u16* Kb = Kf + ((size_t)b * 64) * 1024 * 8;
  const u16* Vb = Vf + ((size_t)b * 64) * 1024 * 8;

  bf16x8 qf[8];
  {
    const float* Qr = qg + ((size_t)b * Sn + q0 + c) * Dn;
    #pragma unroll
    for (int kc = 0; kc < 8; ++kc) {
      float4 f0 = *(const float4*)(Qr + kc * 16 + h * 8);
      float4 f1 = *(const float4*)(Qr + kc * 16 + h * 8 + 4);
      uint4 t;
      t.x = pk2(f0.x * SCL2E, f0.y * SCL2E);
      t.y = pk2(f0.z * SCL2E, f0.w * SCL2E);
      t.z = pk2(f1.x * SCL2E, f1.y * SCL2E);
      t.w = pk2(f1.z * SCL2E, f1.w * SCL2E);
      qf[kc] = __builtin_bit_cast(bf16x8, t);
    }
  }

  f32x16 accO[4];
  #pragma unroll
  for (int nt = 0; nt < 4; ++nt)
    #pragma unroll
    for (int r = 0; r < 16; ++r) accO[nt][r] = 0.f;
  float l_i = 0.f;

  #pragma unroll 1
  for (int t8 = 0; t8 < 16; ++t8) {
    const int kt = kp * 16 + t8;
    const u16* Kt = Kb + (size_t)kt * 8192;
    const u16* Vt = Vb + (size_t)kt * 8192;

    uint4 ka[8], kb[8];
    #pragma unroll
    for (int kc = 0; kc < 4; ++kc) {
      ka[2 * kc + 0] = *(const uint4*)(Kt + (size_t)((kc * 4 + 0 + h) * 32 + c) * 8);
      ka[2 * kc + 1] = *(const uint4*)(Kt + (size_t)((kc * 4 + 2 + h) * 32 + c) * 8);
    }
    #pragma unroll
    for (int kc = 4; kc < 8; ++kc) {
      kb[2 * (kc - 4) + 0] = *(const uint4*)(Kt + (size_t)((kc * 4 + 0 + h) * 32 + c) * 8);
      kb[2 * (kc - 4) + 1] = *(const uint4*)(Kt + (size_t)((kc * 4 + 2 + h) * 32 + c) * 8);
    }

    f32x16 sa0, sa1;
    #pragma unroll
    for (int r = 0; r < 16; ++r) { sa0[r] = 0.f; sa1[r] = 0.f; }
    #pragma unroll
    for (int kc = 0; kc < 4; ++kc) {
      sa0 = __builtin_amdgcn_mfma_f32_32x32x16_bf16(__builtin_bit_cast(bf16x8, ka[2 * kc + 0]), qf[kc], sa0, 0, 0, 0);
      sa1 = __builtin_amdgcn_mfma_f32_32x32x16_bf16(__builtin_bit_cast(bf16x8, ka[2 * kc + 1]), qf[kc], sa1, 0, 0, 0);
    }
    uint4 va[8];
    #pragma unroll
    for (int kc2 = 0; kc2 < 2; ++kc2)
      #pragma unroll
      for (int nt = 0; nt < 4; ++nt)
        va[kc2 * 4 + nt] = *(const uint4*)(Vt + (size_t)((kc2 * 8 + nt * 2 + h) * 32 + c) * 8);
    #pragma unroll
    for (int kc = 4; kc < 8; ++kc) {
      sa0 = __builtin_amdgcn_mfma_f32_32x32x16_bf16(__builtin_bit_cast(bf16x8, kb[2 * (kc - 4) + 0]), qf[kc], sa0, 0, 0, 0);
      sa1 = __builtin_amdgcn_mfma_f32_32x32x16_bf16(__builtin_bit_cast(bf16x8, kb[2 * (kc - 4) + 1]), qf[kc], sa1, 0, 0, 0);
    }
    uint4 vb[8];
    #pragma unroll
    for (int kc2 = 2; kc2 < 4; ++kc2)
      #pragma unroll
      for (int nt = 0; nt < 4; ++nt)
        vb[(kc2 - 2) * 4 + nt] = *(const uint4*)(Vt + (size_t)((kc2 * 8 + nt * 2 + h) * 32 + c) * 8);

    float rs0 = 0.f, rs1 = 0.f;
    #pragma unroll
    for (int r = 0; r < 16; ++r) { sa0[r] = exp2f(sa0[r]); rs0 += sa0[r]; }
    #pragma unroll
    for (int r = 0; r < 16; ++r) { sa1[r] = exp2f(sa1[r]); rs1 += sa1[r]; }
    l_i += rs0 + rs1;

    u32 pk2v[2][8];
    #pragma unroll
    for (int i = 0; i < 8; ++i) {
      pk2v[0][i] = pk2(sa0[2 * i], sa0[2 * i + 1]);
      pk2v[1][i] = pk2(sa1[2 * i], sa1[2 * i + 1]);
    }

    #pragma unroll
    for (int kc2 = 0; kc2 < 4; ++kc2) {
      const int t = kc2 >> 1;
      const int bb = (kc2 & 1) * 4;
      u32 x0 = pk2v[t][bb], x1 = pk2v[t][bb + 1], x2 = pk2v[t][bb + 2], x3 = pk2v[t][bb + 3];
      pl32swap(x0, x2);
      pl32swap(x1, x3);
      uint4 afi; afi.x = x0; afi.y = x1; afi.z = x2; afi.w = x3;
      bf16x8 af = __builtin_bit_cast(bf16x8, afi);
      const uint4* vsrc = (kc2 < 2) ? &va[kc2 * 4] : &vb[(kc2 - 2) * 4];
      #pragma unroll
      for (int nt = 0; nt < 4; ++nt) {
        accO[nt] = __builtin_amdgcn_mfma_f32_32x32x16_bf16(__builtin_bit_cast(bf16x8, vsrc[nt]), af, accO[nt], 0, 0, 0);
      }
    }
  }

  l_i += __shfl_xor(l_i, 32);
  __syncthreads();
  {
    float* od = Oc + (size_t)(kp * 32) * OSTR;
    #pragma unroll
    for (int nt = 0; nt < 4; ++nt)
      #pragma unroll
      for (int r = 0; r < 16; ++r) {
        const int dr = (r & 3) + 8 * (r >> 2) + 4 * h;
        od[c * OSTR + nt * 32 + dr] = accO[nt][r];
      }
    if (h == 0) ml[kp * 32 + c] = l_i;
  }
  __syncthreads();
  {
    const int row = tid >> 3;
    const int d0 = (tid & 7) * 16;
    float lsum = 0.f;
    #pragma unroll
    for (int k2 = 0; k2 < 4; ++k2) lsum += ml[k2 * 32 + row];
    const float inv = 1.f / lsum;
    float4 acc[4];
    #pragma unroll
    for (int j = 0; j < 4; ++j) acc[j] = float4{0.f, 0.f, 0.f, 0.f};
    #pragma unroll
    for (int k2 = 0; k2 < 4; ++k2) {
      const float* oc = Oc + (size_t)(k2 * 32 + row) * OSTR + d0;
      #pragma unroll
      for (int j = 0; j < 4; ++j) {
        float4 vv = *(const float4*)(oc + 4 * j);
        acc[j].x += vv.x; acc[j].y += vv.y;
        acc[j].z += vv.z; acc[j].w += vv.w;
      }
    }
    float* op = Og + ((size_t)b * Sn + q0 + row) * Dn + d0;
    #pragma unroll
    for (int j = 0; j < 4; ++j) {
      float4 o = {acc[j].x * inv, acc[j].y * inv, acc[j].z * inv, acc[j].w * inv};
      *(float4*)(op + 4 * j) = o;
    }
  }
}

extern "C" void kernel_launch(void* const* d_in, const int* in_sizes, int n_in,
                              void* d_out, int out_size, void* d_ws, size_t ws_size,
                              hipStream_t stream) {
  const float* q = (const float*)d_in[0];
  const float* k = (const float*)d_in[1];
  const float* v = (const float*)d_in[2];
  float* out = (float*)d_out;
  const size_t N = (size_t)Bn * Sn * Dn;  // 2,097,152 elems
  u16* Kf = (u16*)d_ws;                   // 4 MB
  u16* Vf = Kf + N;                       // 4 MB
  u16* Of16 = Vf + N;                     // 16 MB: [4 ks][16384 rows][128 d] bf16
  float* lwp = (float*)(Of16 + 4 * N);    // 256 KB: [4 ks][16384 rows]
  const size_t need = 4 * N               // Kf+Vf bytes
                    + 8 * N               // Of16 bytes
                    + 16 * (size_t)Bn * Sn;  // lw bytes

  prep_kv<<<dim3(Sn / 64, 2, Bn), dim3(256), 0, stream>>>(k, v, Kf, Vf);
  if (ws_size >= need) {
    attn_tile<<<dim3(256), dim3(512), 0, stream>>>(q, Kf, Vf, Of16, lwp);
    combine<<<dim3(1024), dim3(256), 0, stream>>>(Of16, lwp, out);
  } else {
    attn_legacy<<<dim3((Sn / 32) * Bn), dim3(256), 0, stream>>>(q, Kf, Vf, out);
  }
}